// Round 1
// baseline (153.747 us; speedup 1.0000x reference)
//
#include <hip/hip_runtime.h>
#include <cstdint>

// =====================================================================
// MultiHeadAttention_84576495993495  (round 8)
//
// Algebraic collapse: einsum('bhqk,bhvo->bhvo', attn, v) sums attn over
// BOTH q and k; softmax rows sum to 1 -> factor is exactly S=2048.
//   final = x @ (2048*Wp@Wv)^T + (2048*Wp@bv + bp)
// Wq/bq/Wk/bk unused.
//
// R8 (theory: R7's BK=128 @ 2 blocks/CU == learn_hip m132's 508 TF
// regression config; drain latency is hidden by occupancy, not tile
// depth -- m97's BK=32 @ ~3 blocks/CU is the verified 874-912 TF
// structure):
//   - Revert GEMM to m97 structure: BM=BN=128, BK=32, 16 KB LDS,
//     4 global_load_lds(16B)/thread/iter, no launch_bounds cap.
//   - BK=32 swizzle: LDS slot c of row r holds global chunk
//     c ^ ((r>>1)&3) -> ds_read_b128 aliasing drops 8-way -> 2-way
//     (free per m136).
//   - Everything else (XCD grouping, split-K gemm1, prep, reduce)
//     unchanged to isolate the GEMM-structure variable.
// =====================================================================

typedef unsigned short u16;
typedef __bf16 bf16x8 __attribute__((ext_vector_type(8)));
typedef float f32x4 __attribute__((ext_vector_type(4)));

__device__ __forceinline__ u16 f2bf(float f) {
  // round-to-nearest-even f32 -> bf16 bits (finite inputs)
  unsigned int u = __float_as_uint(f);
  u += 0x7fffu + ((u >> 16) & 1u);
  return (u16)(u >> 16);
}

// async global->LDS 16B copy; LDS dest = wave-uniform base + lane*16
__device__ __forceinline__ void load16(const void* g, void* l) {
  auto gp = (const __attribute__((address_space(1))) unsigned int*)(uintptr_t)g;
  auto lp = (__attribute__((address_space(3))) unsigned int*)(unsigned int)(uintptr_t)l;
  __builtin_amdgcn_global_load_lds(gp, lp, 16, 0, 0);
}

// ---------------------------------------------------------------------
// Fused prep. Block ranges:
//   [0,8192)      conv x   f32->bf16 (4 elem/thread)
//   [8192,9216)   conv Wp  f32->bf16
//   [9216,10240)  transpose+conv Wv -> Wv^T bf16 (32x32 tiles)
//   [10240,10496) cv[n] = 2048*dot(Wp[n,:],bv) + bp[n]
__global__ void k_prep(const float* __restrict__ x, const float* __restrict__ Wv,
                       const float* __restrict__ bv, const float* __restrict__ Wp,
                       const float* __restrict__ bp, u16* __restrict__ xb,
                       u16* __restrict__ wpb, u16* __restrict__ wvtb,
                       float* __restrict__ cv) {
  __shared__ float tile[32][33];
  const int b = blockIdx.x;
  const int tid = threadIdx.x;
  if (b < 9216) {  // conversions
    const float* src = (b < 8192) ? x : Wp;
    u16* dst = (b < 8192) ? xb : wpb;
    const long base = (long)((b < 8192) ? b : (b - 8192)) * 1024 + tid * 4;
    const float4 v = *(const float4*)(src + base);
    ushort4 o;
    o.x = f2bf(v.x); o.y = f2bf(v.y); o.z = f2bf(v.z); o.w = f2bf(v.w);
    *(ushort4*)(dst + base) = o;
  } else if (b < 10240) {  // transpose Wv
    const int tb = b - 9216;
    const int bi = (tb & 31) * 32;   // output row block (i)
    const int bj = (tb >> 5) * 32;   // output col block (j) = src row block
    const int tx = tid & 31;
    const int ty = tid >> 5;  // 0..7
    for (int r = ty; r < 32; r += 8)
      tile[r][tx] = Wv[(long)(bj + r) * 1024 + bi + tx];
    __syncthreads();
    for (int r = ty; r < 32; r += 8)
      wvtb[(long)(bi + r) * 1024 + bj + tx] = f2bf(tile[tx][r]);
  } else {  // bias fold
    const int row = (b - 10240) * 4 + (tid >> 6);
    const int lane = tid & 63;
    const float* w = Wp + (long)row * 1024;
    float s = 0.f;
    for (int j = lane; j < 1024; j += 64) s += w[j] * bv[j];
    for (int off = 32; off; off >>= 1) s += __shfl_down(s, off, 64);
    if (lane == 0) cv[row] = 2048.f * s + bp[row];
  }
}

// ---------------------------------------------------------------------
// reduce 4 split-K fp32 partial slabs -> bf16, *2048
__global__ void k_reduce(const float* __restrict__ p, u16* __restrict__ dst) {
  const long i = (long)(blockIdx.x * 256 + threadIdx.x) * 4;
  const float4 a = *(const float4*)(p + i);
  const float4 b = *(const float4*)(p + 1048576 + i);
  const float4 c = *(const float4*)(p + 2097152 + i);
  const float4 d = *(const float4*)(p + 3145728 + i);
  ushort4 o;
  o.x = f2bf((a.x + b.x + c.x + d.x) * 2048.f);
  o.y = f2bf((a.y + b.y + c.y + d.y) * 2048.f);
  o.z = f2bf((a.z + b.z + c.z + d.z) * 2048.f);
  o.w = f2bf((a.w + b.w + c.w + d.w) * 2048.f);
  *(ushort4*)(dst + i) = o;
}

// ---------------------------------------------------------------------
// NT bf16 GEMM: Out[M,N] (+bias) = A[M,K] @ B[N,K]^T
// m97 structure: BM=BN=128, BK=32, 256 threads = 4 waves (2x2), each
// wave a 64x64 sub-tile (4x4 MFMA acc). Per K-iter: 4 global_load_lds
// (16B) per thread + 8 ds_read_b128 + 16 MFMA per wave. 16 KB LDS ->
// occupancy-driven latency hiding (m114), ~3 blocks/CU capacity.
// Swizzle: LDS slot c of row r holds global chunk c ^ ((r>>1)&3), so
// fragment reads alias 2-way (free) instead of 8-way.
// MODE 0: fp32 out + bias, XCD-grouped 1-D grid. MODE 1: split-K slab.
template <int MODE>
__global__ __launch_bounds__(256) void k_gemm(
    const u16* __restrict__ A, const u16* __restrict__ B, float* __restrict__ Out,
    const float* __restrict__ bias, int M, int N, int K) {
  __shared__ u16 As[128 * 32];  // 8 KB
  __shared__ u16 Bs[128 * 32];  // 8 KB

  const int tid = threadIdx.x;
  const int lane = tid & 63;
  const int wv = tid >> 6;
  const int waveM = (wv & 1) << 6;
  const int waveN = (wv >> 1) << 6;
  const int l15 = lane & 15;
  const int quad = lane >> 4;

  long bm, bn;
  int kBeg, kEnd;
  if constexpr (MODE == 0) {
    // XCD grouping: xcd = id&7 owns contiguous m-panels; a panel's
    // (N/128) n-blocks are temporally adjacent on that XCD.
    const int id = blockIdx.x;            // gridDim.x = (M/128)*(N/128)
    const int xcd = id & 7;
    const int j = id >> 3;
    const int nb = N >> 7;
    const int mPerXcd = M / 128 / 8;
    bm = (long)(xcd * mPerXcd + j / nb) * 128;
    bn = (long)(j % nb) * 128;
    kBeg = 0; kEnd = K;
  } else {
    bm = (long)blockIdx.x * 128;
    bn = (long)blockIdx.y * 128;
    const int kChunk = K / gridDim.z;
    kBeg = blockIdx.z * kChunk;
    kEnd = kBeg + kChunk;
  }

  // Staging: 2 calls each for A and B. Call r (0/1) of wave wv fills
  // rows [(r*4+wv)*16, +16) (1 KB, = wave-uniform base + lane*16B).
  // Lane l: row_local = l>>2, LDS slot c = l&3, fetches global chunk
  // cs = c ^ ((l>>3)&3)   [ (l>>3)&3 == (row>>1)&3 within the group ].
  const int rl = lane >> 2;
  const int cs = (lane & 3) ^ ((lane >> 3) & 3);
  const u16* Ag0 = A + (bm + wv * 16 + rl) * (long)K + cs * 8;
  const u16* Bg0 = B + (bn + wv * 16 + rl) * (long)K + cs * 8;
  const long rowOff = 64 * (long)K;     // call r=1: +64 rows
  u16* Asl0 = As + wv * 512;            // rows [wv*16, +16)
  u16* Asl1 = As + 2048 + wv * 512;     // rows [64+wv*16, +16)
  u16* Bsl0 = Bs + wv * 512;
  u16* Bsl1 = Bs + 2048 + wv * 512;

  const f32x4 zero = {0.f, 0.f, 0.f, 0.f};
  f32x4 acc[4][4];
#pragma unroll
  for (int i = 0; i < 4; ++i)
#pragma unroll
    for (int j = 0; j < 4; ++j) acc[i][j] = zero;

  // Fragment read: logical chunk quad of row (..+l15) sits at LDS slot
  // quad ^ ((l15>>1)&3)  (same for all t since 16t, waveM are mult of 8
  // rows).
  const int rq = quad ^ ((l15 >> 1) & 3);

  for (int k0 = kBeg; k0 < kEnd; k0 += 32) {
    __syncthreads();  // previous tile fully consumed
    load16(Ag0 + k0, Asl0);
    load16(Ag0 + rowOff + k0, Asl1);
    load16(Bg0 + k0, Bsl0);
    load16(Bg0 + rowOff + k0, Bsl1);
    __syncthreads();  // staging drained (vmcnt(0) before s_barrier)

    bf16x8 af[4], bg[4];
#pragma unroll
    for (int t = 0; t < 4; ++t) {
      af[t] = *(const bf16x8*)(As + (waveM + t * 16 + l15) * 32 + rq * 8);
      bg[t] = *(const bf16x8*)(Bs + (waveN + t * 16 + l15) * 32 + rq * 8);
    }
#pragma unroll
    for (int i = 0; i < 4; ++i)
#pragma unroll
      for (int j = 0; j < 4; ++j)
        acc[i][j] = __builtin_amdgcn_mfma_f32_16x16x32_bf16(af[i], bg[j], acc[i][j], 0, 0, 0);
  }

  // epilogue: C/D layout col = lane&15, row = quad*4 + reg  [m89/m91]
  float* outp = (MODE == 1) ? Out + (long)blockIdx.z * M * N : Out;
#pragma unroll
  for (int i = 0; i < 4; ++i) {
    const long gm = bm + waveM + i * 16 + quad * 4;
#pragma unroll
    for (int j = 0; j < 4; ++j) {
      const long gn = bn + waveN + j * 16 + l15;
      const float bb = (MODE == 0) ? bias[gn] : 0.f;
#pragma unroll
      for (int r = 0; r < 4; ++r)
        outp[(gm + r) * N + gn] = acc[i][j][r] + bb;
    }
  }
}

// =====================================================================
extern "C" void kernel_launch(void* const* d_in, const int* in_sizes, int n_in,
                              void* d_out, int out_size, void* d_ws, size_t ws_size,
                              hipStream_t stream) {
  // setup_inputs order: x, Wq, bq, Wk, bk, Wv, bv, Wp, bp
  const float* x  = (const float*)d_in[0];
  const float* Wv = (const float*)d_in[5];
  const float* bv = (const float*)d_in[6];
  const float* Wp = (const float*)d_in[7];
  const float* bp = (const float*)d_in[8];

  char* ws = (char*)d_ws;
  u16* xb    = (u16*)(ws);                      // 16 MB  x bf16
  u16* wpb   = (u16*)(ws + (16u << 20));        //  2 MB  Wp bf16
  u16* wvtb  = (u16*)(ws + (18u << 20));        //  2 MB  Wv^T bf16
  u16* m2b   = (u16*)(ws + (20u << 20));        //  2 MB  M2 bf16
  float* cv  = (float*)(ws + (22u << 20));      //  4 KB  folded bias
  float* m2f = (float*)(ws + (22u << 20) + 4096);  // 16 MB split-K partials

  // 1) fused prep: conv x / conv Wp / transpose Wv / bias fold
  k_prep<<<10496, 256, 0, stream>>>(x, Wv, bv, Wp, bp, xb, wpb, wvtb, cv);

  // 2) M2 partials = Wp @ Wv  (split-K=4: 8x8x4 = 256 blocks, 8 iters each)
  k_gemm<1><<<dim3(8, 8, 4), 256, 0, stream>>>(wpb, wvtb, m2f, nullptr,
                                               1024, 1024, 1024);
  // 3) M2 = bf16(2048 * sum of partials)
  k_reduce<<<1024, 256, 0, stream>>>(m2f, m2b);

  // 4) out = x @ M2^T + cv  (64 panels x 8 n-blocks = 512, XCD-grouped)
  k_gemm<0><<<512, 256, 0, stream>>>(xb, m2b, (float*)d_out, cv,
                                     8192, 1024, 1024);
}

// Round 2
// 145.374 us; speedup vs baseline: 1.0576x; 1.0576x over previous
//
#include <hip/hip_runtime.h>
#include <cstdint>

// =====================================================================
// MultiHeadAttention_84576495993495  (round 9)
//
// Algebraic collapse: einsum('bhqk,bhvo->bhvo', attn, v) sums attn over
// BOTH q and k; softmax rows sum to 1 -> factor is exactly S=2048.
//   final = x @ (2048*Wp@Wv)^T + (2048*Wp@bv + bp)
// Wq/bq/Wk/bk unused.
//
// R9 theory: R7 (BK=128, 8 drains) beat R8 (BK=32, 32 drains) => the
// per-iter vmcnt(0) drain is the bottleneck at 2 blocks/CU (grid 512).
// Fix = T3+T4 minimal pipeline (m218: counted vmcnt +38-73% vs drain0):
//   - 3 LDS buffers (3 x 16 KB = 48 KB), stage tiles 2 ahead.
//   - Main loop waits s_waitcnt vmcnt(8) -- only the OLDEST tile's 4
//     loads; the next 2 tiles' 8 loads stay in flight across barriers.
//   - Raw s_barrier pair per iter:  barrier1 = tile t visible to all;
//     barrier2 = all waves done reading buf(t%3) before stage(t+3)
//     (issued next iter) can overwrite it. Safe for all interleavings.
//   - Everything else (swizzle, XCD grouping, split-K gemm1, prep,
//     reduce) unchanged from R8 to isolate the pipeline variable.
// =====================================================================

typedef unsigned short u16;
typedef __bf16 bf16x8 __attribute__((ext_vector_type(8)));
typedef float f32x4 __attribute__((ext_vector_type(4)));

__device__ __forceinline__ u16 f2bf(float f) {
  // round-to-nearest-even f32 -> bf16 bits (finite inputs)
  unsigned int u = __float_as_uint(f);
  u += 0x7fffu + ((u >> 16) & 1u);
  return (u16)(u >> 16);
}

// async global->LDS 16B copy; LDS dest = wave-uniform base + lane*16
__device__ __forceinline__ void load16(const void* g, void* l) {
  auto gp = (const __attribute__((address_space(1))) unsigned int*)(uintptr_t)g;
  auto lp = (__attribute__((address_space(3))) unsigned int*)(unsigned int)(uintptr_t)l;
  __builtin_amdgcn_global_load_lds(gp, lp, 16, 0, 0);
}

// ---------------------------------------------------------------------
// Fused prep. Block ranges:
//   [0,8192)      conv x   f32->bf16 (4 elem/thread)
//   [8192,9216)   conv Wp  f32->bf16
//   [9216,10240)  transpose+conv Wv -> Wv^T bf16 (32x32 tiles)
//   [10240,10496) cv[n] = 2048*dot(Wp[n,:],bv) + bp[n]
__global__ void k_prep(const float* __restrict__ x, const float* __restrict__ Wv,
                       const float* __restrict__ bv, const float* __restrict__ Wp,
                       const float* __restrict__ bp, u16* __restrict__ xb,
                       u16* __restrict__ wpb, u16* __restrict__ wvtb,
                       float* __restrict__ cv) {
  __shared__ float tile[32][33];
  const int b = blockIdx.x;
  const int tid = threadIdx.x;
  if (b < 9216) {  // conversions
    const float* src = (b < 8192) ? x : Wp;
    u16* dst = (b < 8192) ? xb : wpb;
    const long base = (long)((b < 8192) ? b : (b - 8192)) * 1024 + tid * 4;
    const float4 v = *(const float4*)(src + base);
    ushort4 o;
    o.x = f2bf(v.x); o.y = f2bf(v.y); o.z = f2bf(v.z); o.w = f2bf(v.w);
    *(ushort4*)(dst + base) = o;
  } else if (b < 10240) {  // transpose Wv
    const int tb = b - 9216;
    const int bi = (tb & 31) * 32;   // output row block (i)
    const int bj = (tb >> 5) * 32;   // output col block (j) = src row block
    const int tx = tid & 31;
    const int ty = tid >> 5;  // 0..7
    for (int r = ty; r < 32; r += 8)
      tile[r][tx] = Wv[(long)(bj + r) * 1024 + bi + tx];
    __syncthreads();
    for (int r = ty; r < 32; r += 8)
      wvtb[(long)(bi + r) * 1024 + bj + tx] = f2bf(tile[tx][r]);
  } else {  // bias fold
    const int row = (b - 10240) * 4 + (tid >> 6);
    const int lane = tid & 63;
    const float* w = Wp + (long)row * 1024;
    float s = 0.f;
    for (int j = lane; j < 1024; j += 64) s += w[j] * bv[j];
    for (int off = 32; off; off >>= 1) s += __shfl_down(s, off, 64);
    if (lane == 0) cv[row] = 2048.f * s + bp[row];
  }
}

// ---------------------------------------------------------------------
// reduce 4 split-K fp32 partial slabs -> bf16, *2048
__global__ void k_reduce(const float* __restrict__ p, u16* __restrict__ dst) {
  const long i = (long)(blockIdx.x * 256 + threadIdx.x) * 4;
  const float4 a = *(const float4*)(p + i);
  const float4 b = *(const float4*)(p + 1048576 + i);
  const float4 c = *(const float4*)(p + 2097152 + i);
  const float4 d = *(const float4*)(p + 3145728 + i);
  ushort4 o;
  o.x = f2bf((a.x + b.x + c.x + d.x) * 2048.f);
  o.y = f2bf((a.y + b.y + c.y + d.y) * 2048.f);
  o.z = f2bf((a.z + b.z + c.z + d.z) * 2048.f);
  o.w = f2bf((a.w + b.w + c.w + d.w) * 2048.f);
  *(ushort4*)(dst + i) = o;
}

// ---------------------------------------------------------------------
// NT bf16 GEMM: Out[M,N] (+bias) = A[M,K] @ B[N,K]^T
// BM=BN=128, BK=32, 256 threads = 4 waves (2x2), each wave 64x64
// (4x4 MFMA acc).  Depth-2 software pipeline (T3+T4 minimal):
//   3 LDS buffers; iter t issues stage(t+2), waits vmcnt(8) (= only
//   tile t's 4 loads; 8 newer loads stay in flight across barriers),
//   barrier, ds_read+MFMA, barrier.  Never vmcnt(0) in the main loop.
// Swizzle: LDS slot c of row r holds global chunk c ^ ((r>>1)&3), so
// fragment ds_read_b128 aliases 2-way (free, m136) instead of 8-way.
// MODE 0: fp32 out + bias, XCD-grouped 1-D grid. MODE 1: split-K slab.
template <int MODE>
__global__ __launch_bounds__(256) void k_gemm(
    const u16* __restrict__ A, const u16* __restrict__ B, float* __restrict__ Out,
    const float* __restrict__ bias, int M, int N, int K) {
  __shared__ u16 As[3][128 * 32];  // 3 x 8 KB
  __shared__ u16 Bs[3][128 * 32];  // 3 x 8 KB

  const int tid = threadIdx.x;
  const int lane = tid & 63;
  const int wv = tid >> 6;
  const int waveM = (wv & 1) << 6;
  const int waveN = (wv >> 1) << 6;
  const int l15 = lane & 15;
  const int quad = lane >> 4;

  long bm, bn;
  int kBeg, kEnd;
  if constexpr (MODE == 0) {
    // XCD grouping: xcd = id&7 owns contiguous m-panels; a panel's
    // (N/128) n-blocks are temporally adjacent on that XCD.
    const int id = blockIdx.x;            // gridDim.x = (M/128)*(N/128)
    const int xcd = id & 7;
    const int j = id >> 3;
    const int nb = N >> 7;
    const int mPerXcd = M / 128 / 8;
    bm = (long)(xcd * mPerXcd + j / nb) * 128;
    bn = (long)(j % nb) * 128;
    kBeg = 0; kEnd = K;
  } else {
    bm = (long)blockIdx.x * 128;
    bn = (long)blockIdx.y * 128;
    const int kChunk = K / gridDim.z;
    kBeg = blockIdx.z * kChunk;
    kEnd = kBeg + kChunk;
  }

  // Staging: 2 calls each for A and B per tile. Call r (0/1) of wave wv
  // fills rows [(r*4+wv)*16, +16) (1 KB = wave-uniform base + lane*16B).
  // Lane l: row_local = l>>2, LDS slot c = l&3, fetches global chunk
  // cs = c ^ ((l>>3)&3)   [ (l>>3)&3 == (row>>1)&3 within the group ].
  const int rl = lane >> 2;
  const int cs = (lane & 3) ^ ((lane >> 3) & 3);
  const u16* Ag0 = A + (bm + wv * 16 + rl) * (long)K + cs * 8;
  const u16* Bg0 = B + (bn + wv * 16 + rl) * (long)K + cs * 8;
  const long rowOff = 64 * (long)K;     // call r=1: +64 rows

  const int nT = (kEnd - kBeg) >> 5;    // # K-tiles

  // stage tile tt into buffer b (4 x global_load_lds, 16B each)
  auto STAGE = [&](int tt, int b) {
    const long k0 = (long)kBeg + ((long)tt << 5);
    u16* Ad = &As[b][0] + (wv << 9);
    u16* Bd = &Bs[b][0] + (wv << 9);
    load16(Ag0 + k0, Ad);
    load16(Ag0 + rowOff + k0, Ad + 2048);
    load16(Bg0 + k0, Bd);
    load16(Bg0 + rowOff + k0, Bd + 2048);
  };

  const f32x4 zero = {0.f, 0.f, 0.f, 0.f};
  f32x4 acc[4][4];
#pragma unroll
  for (int i = 0; i < 4; ++i)
#pragma unroll
    for (int j = 0; j < 4; ++j) acc[i][j] = zero;

  // Fragment read: logical chunk quad of row (..+l15) sits at LDS slot
  // quad ^ ((l15>>1)&3)  (same for all t: 16t, waveM are mults of 8 rows).
  const int rq = quad ^ ((l15 >> 1) & 3);

  // ---- prologue: stage tiles 0 and 1 ----
  STAGE(0, 0);
  if (nT > 1) STAGE(1, 1);

  int cb = 0;  // buffer holding tile tt
  for (int tt = 0; tt < nT; ++tt) {
    const int rem = nT - 1 - tt;
    if (rem >= 2) {
      STAGE(tt + 2, cb == 0 ? 2 : cb - 1);   // (tt+2) % 3
      // outstanding: tiles tt,tt+1,tt+2 = 12 loads; wait oldest 4 done
      asm volatile("s_waitcnt vmcnt(8)" ::: "memory");
    } else if (rem == 1) {
      // outstanding: tiles tt,tt+1 = 8 loads; wait oldest 4 done
      asm volatile("s_waitcnt vmcnt(4)" ::: "memory");
    } else {
      asm volatile("s_waitcnt vmcnt(0)" ::: "memory");
    }
    __builtin_amdgcn_s_barrier();  // barrier1: tile tt visible to all waves

    const u16* Asb = &As[cb][0];
    const u16* Bsb = &Bs[cb][0];
    bf16x8 af[4], bg[4];
#pragma unroll
    for (int t = 0; t < 4; ++t) {
      af[t] = *(const bf16x8*)(Asb + (waveM + t * 16 + l15) * 32 + rq * 8);
      bg[t] = *(const bf16x8*)(Bsb + (waveN + t * 16 + l15) * 32 + rq * 8);
    }
#pragma unroll
    for (int i = 0; i < 4; ++i)
#pragma unroll
      for (int j = 0; j < 4; ++j)
        acc[i][j] = __builtin_amdgcn_mfma_f32_16x16x32_bf16(af[i], bg[j], acc[i][j], 0, 0, 0);

    __builtin_amdgcn_s_barrier();  // barrier2: all reads of buf cb done
    cb = (cb == 2) ? 0 : cb + 1;
  }

  // epilogue: C/D layout col = lane&15, row = quad*4 + reg  [m89/m91]
  float* outp = (MODE == 1) ? Out + (long)blockIdx.z * M * N : Out;
#pragma unroll
  for (int i = 0; i < 4; ++i) {
    const long gm = bm + waveM + i * 16 + quad * 4;
#pragma unroll
    for (int j = 0; j < 4; ++j) {
      const long gn = bn + waveN + j * 16 + l15;
      const float bb = (MODE == 0) ? bias[gn] : 0.f;
#pragma unroll
      for (int r = 0; r < 4; ++r)
        outp[(gm + r) * N + gn] = acc[i][j][r] + bb;
    }
  }
}

// =====================================================================
extern "C" void kernel_launch(void* const* d_in, const int* in_sizes, int n_in,
                              void* d_out, int out_size, void* d_ws, size_t ws_size,
                              hipStream_t stream) {
  // setup_inputs order: x, Wq, bq, Wk, bk, Wv, bv, Wp, bp
  const float* x  = (const float*)d_in[0];
  const float* Wv = (const float*)d_in[5];
  const float* bv = (const float*)d_in[6];
  const float* Wp = (const float*)d_in[7];
  const float* bp = (const float*)d_in[8];

  char* ws = (char*)d_ws;
  u16* xb    = (u16*)(ws);                      // 16 MB  x bf16
  u16* wpb   = (u16*)(ws + (16u << 20));        //  2 MB  Wp bf16
  u16* wvtb  = (u16*)(ws + (18u << 20));        //  2 MB  Wv^T bf16
  u16* m2b   = (u16*)(ws + (20u << 20));        //  2 MB  M2 bf16
  float* cv  = (float*)(ws + (22u << 20));      //  4 KB  folded bias
  float* m2f = (float*)(ws + (22u << 20) + 4096);  // 16 MB split-K partials

  // 1) fused prep: conv x / conv Wp / transpose Wv / bias fold
  k_prep<<<10496, 256, 0, stream>>>(x, Wv, bv, Wp, bp, xb, wpb, wvtb, cv);

  // 2) M2 partials = Wp @ Wv  (split-K=4: 8x8x4 = 256 blocks, 8 iters each)
  k_gemm<1><<<dim3(8, 8, 4), 256, 0, stream>>>(wpb, wvtb, m2f, nullptr,
                                               1024, 1024, 1024);
  // 3) M2 = bf16(2048 * sum of partials)
  k_reduce<<<1024, 256, 0, stream>>>(m2f, m2b);

  // 4) out = x @ M2^T + cv  (64 panels x 8 n-blocks = 512, XCD-grouped)
  k_gemm<0><<<512, 256, 0, stream>>>(xb, m2b, (float*)d_out, cv,
                                     8192, 1024, 1024);
}

// Round 3
// 140.482 us; speedup vs baseline: 1.0944x; 1.0348x over previous
//
#include <hip/hip_runtime.h>
#include <cstdint>

// =====================================================================
// MultiHeadAttention_84576495993495  (round 10)
//
// Algebraic collapse: einsum('bhqk,bhvo->bhvo', attn, v) sums attn over
// BOTH q and k; softmax rows sum to 1 -> factor is exactly S=2048.
//   final = x @ (2048*Wp@Wv)^T + (2048*Wp@bv + bp)
// Wq/bq/Wk/bk unused.
//
// R10: exact 2-phase pipeline recipe (guide T3 box, m248v2 refcheck'd):
//   per iter: STAGE(t+1) -> ds_read(t) -> lgkmcnt(0)+sched_barrier ->
//   32 MFMA -> vmcnt(0) -> s_barrier.  vmcnt AFTER compute = next
//   tile's HBM/L2 latency hides under this tile's MFMA phase (R9 had
//   the wait BEFORE compute -- zero overlap, hence no win vs R7).
//   - BK=64: 2 x 32 KB buffers = 64 KB LDS -> 2 blocks/CU, exactly the
//     512-block grid's residency (no occupancy loss, m132 n/a).
//   - Swizzle: stored chunk = c ^ (row&7)  (8 x 16B chunks/row) ->
//     fragment ds_read_b128 2-way conflict (free). Inverse perm on the
//     global source address (both-sides rule m104/m231).
//   - gemm1 direct (no split-K): 64 blocks, epilogue writes bf16*2048.
//     k_reduce + 16 MB partial slab deleted (one fewer dispatch).
// =====================================================================

typedef unsigned short u16;
typedef __bf16 bf16x8 __attribute__((ext_vector_type(8)));
typedef float f32x4 __attribute__((ext_vector_type(4)));

__device__ __forceinline__ u16 f2bf(float f) {
  // round-to-nearest-even f32 -> bf16 bits (finite inputs)
  unsigned int u = __float_as_uint(f);
  u += 0x7fffu + ((u >> 16) & 1u);
  return (u16)(u >> 16);
}

// async global->LDS 16B copy; LDS dest = wave-uniform base + lane*16
__device__ __forceinline__ void load16(const void* g, void* l) {
  auto gp = (const __attribute__((address_space(1))) unsigned int*)(uintptr_t)g;
  auto lp = (__attribute__((address_space(3))) unsigned int*)(unsigned int)(uintptr_t)l;
  __builtin_amdgcn_global_load_lds(gp, lp, 16, 0, 0);
}

// ---------------------------------------------------------------------
// Fused prep. Block ranges:
//   [0,8192)      conv x   f32->bf16 (4 elem/thread)
//   [8192,9216)   conv Wp  f32->bf16
//   [9216,10240)  transpose+conv Wv -> Wv^T bf16 (32x32 tiles)
//   [10240,10496) cv[n] = 2048*dot(Wp[n,:],bv) + bp[n]
__global__ void k_prep(const float* __restrict__ x, const float* __restrict__ Wv,
                       const float* __restrict__ bv, const float* __restrict__ Wp,
                       const float* __restrict__ bp, u16* __restrict__ xb,
                       u16* __restrict__ wpb, u16* __restrict__ wvtb,
                       float* __restrict__ cv) {
  __shared__ float tile[32][33];
  const int b = blockIdx.x;
  const int tid = threadIdx.x;
  if (b < 9216) {  // conversions
    const float* src = (b < 8192) ? x : Wp;
    u16* dst = (b < 8192) ? xb : wpb;
    const long base = (long)((b < 8192) ? b : (b - 8192)) * 1024 + tid * 4;
    const float4 v = *(const float4*)(src + base);
    ushort4 o;
    o.x = f2bf(v.x); o.y = f2bf(v.y); o.z = f2bf(v.z); o.w = f2bf(v.w);
    *(ushort4*)(dst + base) = o;
  } else if (b < 10240) {  // transpose Wv
    const int tb = b - 9216;
    const int bi = (tb & 31) * 32;   // output row block (i)
    const int bj = (tb >> 5) * 32;   // output col block (j) = src row block
    const int tx = tid & 31;
    const int ty = tid >> 5;  // 0..7
    for (int r = ty; r < 32; r += 8)
      tile[r][tx] = Wv[(long)(bj + r) * 1024 + bi + tx];
    __syncthreads();
    for (int r = ty; r < 32; r += 8)
      wvtb[(long)(bi + r) * 1024 + bj + tx] = f2bf(tile[tx][r]);
  } else {  // bias fold
    const int row = (b - 10240) * 4 + (tid >> 6);
    const int lane = tid & 63;
    const float* w = Wp + (long)row * 1024;
    float s = 0.f;
    for (int j = lane; j < 1024; j += 64) s += w[j] * bv[j];
    for (int off = 32; off; off >>= 1) s += __shfl_down(s, off, 64);
    if (lane == 0) cv[row] = 2048.f * s + bp[row];
  }
}

// ---------------------------------------------------------------------
// NT bf16 GEMM: Out[M,N] = A[M,K] @ B[N,K]^T  (+bias or *2048->bf16)
// BM=BN=128, BK=64, 256 threads = 4 waves (2x2), each wave 64x64
// (4x4 MFMA acc, 32 MFMA per iter).  2-phase counted-vmcnt pipeline.
// LDS: slot c of row r holds global chunk c ^ (r&7); fragment read of
// logical chunk (kk*4+quad) of row (..+l15) uses slot ^ (l15&7).
// MODE 0: f32 out + bias, XCD-grouped 1-D grid (512 blocks).
// MODE 1: bf16 out * 2048 (weight product), plain 64-block grid.
template <int MODE>
__global__ __launch_bounds__(256) void k_gemm(
    const u16* __restrict__ A, const u16* __restrict__ B, void* __restrict__ OutV,
    const float* __restrict__ bias, int M, int N, int K) {
  __shared__ u16 As[2][128 * 64];  // 2 x 16 KB
  __shared__ u16 Bs[2][128 * 64];  // 2 x 16 KB

  const int tid = threadIdx.x;
  const int lane = tid & 63;
  const int wv = tid >> 6;
  const int waveM = (wv & 1) << 6;
  const int waveN = (wv >> 1) << 6;
  const int l15 = lane & 15;
  const int quad = lane >> 4;

  long bm, bn;
  if constexpr (MODE == 0) {
    // XCD grouping: xcd = id&7 owns 8 contiguous m-panels; a panel's 8
    // n-blocks are temporally adjacent on that XCD (B = 2 MB L2-fits).
    const int id = blockIdx.x;            // gridDim.x = (M/128)*(N/128)
    const int xcd = id & 7;
    const int j = id >> 3;
    const int nb = N >> 7;
    const int mPerXcd = M / 128 / 8;
    bm = (long)(xcd * mPerXcd + j / nb) * 128;
    bn = (long)(j % nb) * 128;
  } else {
    // 64 blocks: id&7 = n-block -> round-robin puts one n-column per
    // XCD; B panel reused within its XCD's L2.
    bm = (long)(blockIdx.x >> 3) * 128;
    bn = (long)(blockIdx.x & 7) * 128;
  }

  // Staging: 4 calls each for A and B per tile. Call r of wave wv fills
  // rows [(r*4+wv)*8, +8) (1 KB = wave-uniform base + lane*16B).
  // Lane l: row_local = l>>3 (0..7), LDS slot = l&7, fetches global
  // chunk cs = (l&7) ^ (l>>3)   [row&7 == l>>3: base rows are mult of 8]
  const int rsl = lane >> 3;
  const int cs = (lane & 7) ^ rsl;
  const u16* Ag0 = A + (bm + wv * 8 + rsl) * (long)K + cs * 8;
  const u16* Bg0 = B + (bn + wv * 8 + rsl) * (long)K + cs * 8;

  const int nT = K >> 6;  // # K-tiles

  // stage tile at k-offset k0 into buffer b (8 x global_load_lds, 16B)
  auto STAGE = [&](long k0, int b) {
    u16* Ad = &As[b][0] + (wv << 9);
    u16* Bd = &Bs[b][0] + (wv << 9);
#pragma unroll
    for (int r = 0; r < 4; ++r) {
      load16(Ag0 + k0 + (long)(r * 32) * K, Ad + (r << 11));
      load16(Bg0 + k0 + (long)(r * 32) * K, Bd + (r << 11));
    }
  };

  const f32x4 zero = {0.f, 0.f, 0.f, 0.f};
  f32x4 acc[4][4];
#pragma unroll
  for (int i = 0; i < 4; ++i)
#pragma unroll
    for (int j = 0; j < 4; ++j) acc[i][j] = zero;

  // Fragment read slots (swizzled): logical chunk kk*4+quad, row l15
  const int rq0 = quad ^ (l15 & 7);        // kk = 0
  const int rq1 = (4 + quad) ^ (l15 & 7);  // kk = 1

  // ---- prologue: stage tile 0, drain once, barrier ----
  STAGE(0, 0);
  asm volatile("s_waitcnt vmcnt(0)" ::: "memory");
  __builtin_amdgcn_s_barrier();

  int cur = 0;
  for (int t = 0; t < nT; ++t) {
    const bool more = (t + 1) < nT;
    if (more) STAGE((long)(t + 1) << 6, cur ^ 1);
    __builtin_amdgcn_sched_barrier(0);  // keep stage issue ahead of reads

    const u16* Asb = &As[cur][0];
    const u16* Bsb = &Bs[cur][0];
    bf16x8 af[2][4], bg[2][4];
#pragma unroll
    for (int tt = 0; tt < 4; ++tt) {
      const int ra = (waveM + tt * 16 + l15) * 64;
      const int rb = (waveN + tt * 16 + l15) * 64;
      af[0][tt] = *(const bf16x8*)(Asb + ra + rq0 * 8);
      af[1][tt] = *(const bf16x8*)(Asb + ra + rq1 * 8);
      bg[0][tt] = *(const bf16x8*)(Bsb + rb + rq0 * 8);
      bg[1][tt] = *(const bf16x8*)(Bsb + rb + rq1 * 8);
    }
    asm volatile("s_waitcnt lgkmcnt(0)" ::: "memory");
    __builtin_amdgcn_sched_barrier(0);  // rule #18: don't hoist MFMA past wait

#pragma unroll
    for (int kk = 0; kk < 2; ++kk)
#pragma unroll
      for (int i = 0; i < 4; ++i)
#pragma unroll
        for (int j = 0; j < 4; ++j)
          acc[i][j] = __builtin_amdgcn_mfma_f32_16x16x32_bf16(af[kk][i], bg[kk][j],
                                                              acc[i][j], 0, 0, 0);

    if (more) {
      // next tile's 8 loads had the whole read+MFMA phase to land
      asm volatile("s_waitcnt vmcnt(0)" ::: "memory");
      __builtin_amdgcn_s_barrier();
      cur ^= 1;
    }
  }

  // epilogue: C/D layout col = lane&15, row = quad*4 + reg  [m89/m91]
#pragma unroll
  for (int i = 0; i < 4; ++i) {
    const long gm = bm + waveM + i * 16 + quad * 4;
#pragma unroll
    for (int j = 0; j < 4; ++j) {
      const long gn = bn + waveN + j * 16 + l15;
      if constexpr (MODE == 0) {
        float* outp = (float*)OutV;
        const float bb = bias[gn];
#pragma unroll
        for (int r = 0; r < 4; ++r)
          outp[(gm + r) * N + gn] = acc[i][j][r] + bb;
      } else {
        u16* outp = (u16*)OutV;
#pragma unroll
        for (int r = 0; r < 4; ++r)
          outp[(gm + r) * N + gn] = f2bf(acc[i][j][r] * 2048.f);
      }
    }
  }
}

// =====================================================================
extern "C" void kernel_launch(void* const* d_in, const int* in_sizes, int n_in,
                              void* d_out, int out_size, void* d_ws, size_t ws_size,
                              hipStream_t stream) {
  // setup_inputs order: x, Wq, bq, Wk, bk, Wv, bv, Wp, bp
  const float* x  = (const float*)d_in[0];
  const float* Wv = (const float*)d_in[5];
  const float* bv = (const float*)d_in[6];
  const float* Wp = (const float*)d_in[7];
  const float* bp = (const float*)d_in[8];

  char* ws = (char*)d_ws;
  u16* xb    = (u16*)(ws);                      // 16 MB  x bf16
  u16* wpb   = (u16*)(ws + (16u << 20));        //  2 MB  Wp bf16
  u16* wvtb  = (u16*)(ws + (18u << 20));        //  2 MB  Wv^T bf16
  u16* m2b   = (u16*)(ws + (20u << 20));        //  2 MB  M2 bf16
  float* cv  = (float*)(ws + (22u << 20));      //  4 KB  folded bias

  // 1) fused prep: conv x / conv Wp / transpose Wv / bias fold
  k_prep<<<10496, 256, 0, stream>>>(x, Wv, bv, Wp, bp, xb, wpb, wvtb, cv);

  // 2) M2 = bf16(2048 * Wp @ Wv)  (direct, 8x8 blocks, 16 iters each)
  k_gemm<1><<<64, 256, 0, stream>>>(wpb, wvtb, m2b, nullptr, 1024, 1024, 1024);

  // 3) out = x @ M2^T + cv  (64 panels x 8 n-blocks = 512, XCD-grouped)
  k_gemm<0><<<512, 256, 0, stream>>>(xb, m2b, d_out, cv, 8192, 1024, 1024);
}